// Round 8
// baseline (277.060 us; speedup 1.0000x reference)
//
#include <hip/hip_runtime.h>
#include <hip/hip_bf16.h>

// Problem constants
#define B 8
#define H 3584
#define NH 28
#define KVH 4
#define HD 128
#define GS 7
#define MB 16
#define BS 256
#define R 32           // B*KVH
#define NCHUNK 64      // MB*BS/64 chunks of 64 tokens per row
#define SCALE 0.08838834764831845f

__device__ __forceinline__ float dot4(float4 a, float4 b) {
    return fmaf(a.x, b.x, fmaf(a.y, b.y, fmaf(a.z, b.z, a.w * b.w)));
}

// Sum across a 16-lane DPP row; every lane in the row ends with the row sum.
__device__ __forceinline__ float red16(float v) {
    v += __int_as_float(__builtin_amdgcn_update_dpp(0, __float_as_int(v), 0xB1,  0xf, 0xf, false)); // quad_perm [1,0,3,2]
    v += __int_as_float(__builtin_amdgcn_update_dpp(0, __float_as_int(v), 0x4E,  0xf, 0xf, false)); // quad_perm [2,3,0,1]
    v += __int_as_float(__builtin_amdgcn_update_dpp(0, __float_as_int(v), 0x141, 0xf, 0xf, false)); // row_half_mirror
    v += __int_as_float(__builtin_amdgcn_update_dpp(0, __float_as_int(v), 0x140, 0xf, 0xf, false)); // row_mirror
    return v;
}

__device__ __forceinline__ float4 shfl_xor4(float4 v, int m) {
    float4 r;
    r.x = __shfl_xor(v.x, m);
    r.y = __shfl_xor(v.y, m);
    r.z = __shfl_xor(v.z, m);
    r.w = __shfl_xor(v.w, m);
    return r;
}

// ---------------- Kernel 1: fused QKV GEMV ----------------
__global__ __launch_bounds__(256) void qkv_kernel(
    const float* __restrict__ hid,
    const float* __restrict__ qw, const float* __restrict__ qb,
    const float* __restrict__ kw, const float* __restrict__ kb,
    const float* __restrict__ vw, const float* __restrict__ vb,
    float* __restrict__ qout, float* __restrict__ kout, float* __restrict__ vout)
{
    const int blk = blockIdx.x;
    const int tid = threadIdx.x;
    const int w = tid >> 6;
    const int f0 = blk * 4;

    const float* W; const float* Bv; float* Out; int fbase; int ostr;
    if (blk < 896)       { W = qw; Bv = qb; Out = qout; fbase = f0;        ostr = 3584; }
    else if (blk < 1024) { W = kw; Bv = kb; Out = kout; fbase = f0 - 3584; ostr = 512;  }
    else                 { W = vw; Bv = vb; Out = vout; fbase = f0 - 4096; ostr = 512;  }

    const float4* wr0 = (const float4*)(W + (size_t)(fbase + 0) * H);
    const float4* wr1 = (const float4*)(W + (size_t)(fbase + 1) * H);
    const float4* wr2 = (const float4*)(W + (size_t)(fbase + 2) * H);
    const float4* wr3 = (const float4*)(W + (size_t)(fbase + 3) * H);
    const float4* h4 = (const float4*)hid;

    float acc[4][8];
    #pragma unroll
    for (int i = 0; i < 4; ++i)
        #pragma unroll
        for (int b = 0; b < 8; ++b) acc[i][b] = 0.f;

    #pragma unroll
    for (int k = 0; k < 4; ++k) {
        const int c = tid + k * 256;
        if (c < 896) {
            float4 w0 = wr0[c], w1 = wr1[c], w2 = wr2[c], w3 = wr3[c];
            float4 hb[8];
            #pragma unroll
            for (int b = 0; b < 8; ++b) hb[b] = h4[b * 896 + c];
            #pragma unroll
            for (int b = 0; b < 8; ++b) {
                acc[0][b] += dot4(w0, hb[b]);
                acc[1][b] += dot4(w1, hb[b]);
                acc[2][b] += dot4(w2, hb[b]);
                acc[3][b] += dot4(w3, hb[b]);
            }
        }
    }
    #pragma unroll
    for (int i = 0; i < 4; ++i)
        #pragma unroll
        for (int b = 0; b < 8; ++b)
            #pragma unroll
            for (int m = 1; m < 64; m <<= 1)
                acc[i][b] += __shfl_xor(acc[i][b], m);

    __shared__ float part[4][32];
    if ((tid & 63) == 0) {
        #pragma unroll
        for (int i = 0; i < 4; ++i)
            #pragma unroll
            for (int b = 0; b < 8; ++b)
                part[w][i * 8 + b] = acc[i][b];
    }
    __syncthreads();
    if (tid < 32) {
        const int i = tid >> 3, b = tid & 7;
        const float v = part[0][tid] + part[1][tid] + part[2][tid] + part[3][tid];
        Out[b * ostr + fbase + i] = v + Bv[fbase + i];
    }
}

// ---------------- Kernel 2: flash-decode partials (K via global_load_lds, guaranteed-deep MLP) ----------------
// grid = (NCHUNK, R) blocks of 64 threads (1 wave). No barriers (1-wave block).
// Round-7 evidence: VGPR_Count=128 — the compiler rescheduled the register K-batch
// into shallow sequential batches (in-flight avg ~1.6KB/CU, 1.1TB/s, all pipes <15%).
// Fix: K staged via 32x global_load_lds(16B) — zero VGPR cost, so ALL 32KB is in
// flight before the single vmcnt wait, by construction. LDS dest is linear
// (base+lane*16); the (t&7)<<4 XOR swizzle is applied to the GLOBAL source and the
// LDS read (both-sides involution) to break the 16-way score-read bank conflict.
// LDS 34.5KB/block -> 4 blocks/CU. launch_bounds(64,1): no VGPR cap pressure.
// KV pools READ-ONLY (new token handled in-register from kraw/vraw, as round 7).
__global__ __launch_bounds__(64, 1) void attn_partial_kernel(
    const float* __restrict__ q, const float* __restrict__ kpool, const float* __restrict__ vpool,
    const float* __restrict__ kraw, const float* __restrict__ vraw,
    const float* __restrict__ cosb, const float* __restrict__ sinb,
    const int* __restrict__ btab, const int* __restrict__ cs,
    float* __restrict__ pm, float* __restrict__ pl, float* __restrict__ po)
{
    const int chunk = blockIdx.x;            // 64-token chunk, 0..63
    const int r = blockIdx.y;
    const int seqlen = cs[r];
    const int c0 = chunk << 6;
    if (c0 >= seqlen) return;                // block-uniform (block = 1 wave)
    const int vt = min(64, seqlen - c0);

    const int pos = seqlen - 1;              // the new token's slot
    const bool haspos = (pos >= c0) && (pos < c0 + 64);
    const int tp = pos - c0;                 // local index of pos (valid iff haspos)

    const int lane = threadIdx.x;            // 0..63
    const int page = chunk >> 2;
    const int blk = btab[r * MB + page];
    const int tok0 = (chunk & 3) << 6;       // token offset within 256-token page
    const float* Kp = kpool + ((size_t)blk * BS + tok0) * HD;
    const float* Vp = vpool + ((size_t)blk * BS + tok0) * HD;

    __shared__ float sK[64 * 128];           // 32 KB: K tile, row-major, XOR-swizzled
    __shared__ float s_p[GS][64];            // 1.75 KB

    // ---- Phase A0: issue ALL 32 K global_load_lds (1KB/instr, 32KB total, 0 VGPR) ----
    // instr j, lane l -> LDS byte j*1024 + l*16 = row t = 2j+(l>>5), col (l&31)*16.
    // We store LDS[t][c] = K[t][c ^ ((t&7)<<4)]  (source pre-swizzle; read applies same XOR).
    {
        const int t_lo = lane >> 5;              // 0/1
        const int cbyte = (lane & 31) * 16;      // byte-in-row at dest
        #pragma unroll
        for (int j = 0; j < 32; ++j) {
            const int t = 2 * j + t_lo;
            const int src_byte = cbyte ^ ((t & 7) << 4);
            const float* gsrc = Kp + (size_t)t * HD + (src_byte >> 2);
            __builtin_amdgcn_global_load_lds(
                (const __attribute__((address_space(1))) void*)gsrc,
                (__attribute__((address_space(3))) void*)&sK[j * 256], 16, 0, 0);
        }
    }

    const int tl = lane >> 4;                // token within group of 4
    const int dg = lane & 15;                // dim-group: dims [dg*8, dg*8+8)

    // cos/sin for this lane's 8 dims (shared across all 7 heads)
    const int b = r >> 2;
    const float4 ca = *(const float4*)(cosb + b * HD + dg * 8);
    const float4 cb = *(const float4*)(cosb + b * HD + dg * 8 + 4);
    const float4 sa = *(const float4*)(sinb + b * HD + dg * 8);
    const float4 sb = *(const float4*)(sinb + b * HD + dg * 8 + 4);
    const float sgn = (dg < 8) ? -1.f : 1.f;

    // q fragments: 7 heads x 8 dims per lane, RoPE'd in-register (hides under K flight).
    float4 qa[GS], qb2[GS];
    #pragma unroll
    for (int g = 0; g < GS; ++g) {
        const float4* qp = (const float4*)(q + (size_t)(r * GS + g) * HD + dg * 8);
        float4 xa = qp[0], xb = qp[1];
        float4 oa = shfl_xor4(xa, 8), ob = shfl_xor4(xb, 8);
        qa[g].x  = xa.x * ca.x + sgn * (oa.x * sa.x);
        qa[g].y  = xa.y * ca.y + sgn * (oa.y * sa.y);
        qa[g].z  = xa.z * ca.z + sgn * (oa.z * sa.z);
        qa[g].w  = xa.w * ca.w + sgn * (oa.w * sa.w);
        qb2[g].x = xb.x * cb.x + sgn * (ob.x * sb.x);
        qb2[g].y = xb.y * cb.y + sgn * (ob.y * sb.y);
        qb2[g].z = xb.z * cb.z + sgn * (ob.z * sb.z);
        qb2[g].w = xb.w * cb.w + sgn * (ob.w * sb.w);
    }

    // ---- drain: all K (and q) loads landed; nothing issued after may hoist above ----
    asm volatile("s_waitcnt vmcnt(0)" ::: "memory");
    __builtin_amdgcn_sched_barrier(0);

    // ---- V prefetch batch 1 (tokens 0..31): in flight during the score loop ----
    float2 v1[32];
    #pragma unroll
    for (int t = 0; t < 32; ++t)
        v1[t] = *(const float2*)(Vp + (size_t)t * HD + lane * 2);

    // ---- Phase A: scores from swizzled LDS (16 lanes per token, DPP reduce) ----
    #pragma unroll
    for (int i = 0; i < 16; ++i) {
        const int t = i * 4 + tl;
        const char* row = (const char*)sK + t * 512;
        const int swz = (t & 7) << 4;
        const float4 ka = *(const float4*)(row + ((dg * 32) ^ swz));
        const float4 kb = *(const float4*)(row + ((dg * 32 + 16) ^ swz));
        #pragma unroll
        for (int g = 0; g < GS; ++g) {
            float v = dot4(qa[g], ka) + dot4(qb2[g], kb);
            v = red16(v);
            if (dg == 0) s_p[g][t] = v * SCALE;
        }
    }

    // ---- pos-token score fix-up: rope k from kraw in-register, overwrite s_p[.][tp] ----
    if (haspos) {
        const float* kr = kraw + (size_t)r * HD;
        float4 xa = *(const float4*)(kr + dg * 8);
        float4 xb = *(const float4*)(kr + dg * 8 + 4);
        float4 oa = shfl_xor4(xa, 8), ob = shfl_xor4(xb, 8);
        float4 kna, knb;
        kna.x = xa.x * ca.x + sgn * (oa.x * sa.x);
        kna.y = xa.y * ca.y + sgn * (oa.y * sa.y);
        kna.z = xa.z * ca.z + sgn * (oa.z * sa.z);
        kna.w = xa.w * ca.w + sgn * (oa.w * sa.w);
        knb.x = xb.x * cb.x + sgn * (ob.x * sb.x);
        knb.y = xb.y * cb.y + sgn * (ob.y * sb.y);
        knb.z = xb.z * cb.z + sgn * (ob.z * sb.z);
        knb.w = xb.w * cb.w + sgn * (ob.w * sb.w);
        #pragma unroll
        for (int g = 0; g < GS; ++g) {
            float v = dot4(qa[g], kna) + dot4(qb2[g], knb);
            v = red16(v);
            if (dg == 0) s_p[g][tp] = v * SCALE;   // all 4 DPP-rows write same value
        }
    }
    if (haspos && tp < 32) {
        const float2 vnew = *(const float2*)(vraw + (size_t)r * HD + lane * 2);
        #pragma unroll
        for (int t = 0; t < 32; ++t) { if (tp == t) v1[t] = vnew; }   // static idx, uniform cmp
    }

    // ---- Phase B: per-chunk softmax, lane = token (same wave, no barrier) ----
    const size_t pidx = (size_t)(r * NCHUNK + chunk) * GS;
    #pragma unroll
    for (int g = 0; g < GS; ++g) {
        float sv = (lane < vt) ? s_p[g][lane] : -3.0e38f;
        float m_ = sv;
        #pragma unroll
        for (int m = 1; m < 64; m <<= 1) m_ = fmaxf(m_, __shfl_xor(m_, m));
        float p = (lane < vt) ? __expf(sv - m_) : 0.f;
        s_p[g][lane] = p;                // all 64 slots defined (0 if invalid)
        float l_ = p;
        #pragma unroll
        for (int m = 1; m < 64; m <<= 1) l_ += __shfl_xor(l_, m);
        if (lane == 0) { pm[pidx + g] = m_; pl[pidx + g] = l_; }
    }

    // ---- V prefetch batch 2 (tokens 32..63) ----
    float2 v2[32];
    #pragma unroll
    for (int t = 0; t < 32; ++t)
        v2[t] = *(const float2*)(Vp + (size_t)(32 + t) * HD + lane * 2);
    if (haspos && tp >= 32) {
        const float2 vnew = *(const float2*)(vraw + (size_t)r * HD + lane * 2);
        #pragma unroll
        for (int t = 0; t < 32; ++t) { if (tp == 32 + t) v2[t] = vnew; }
    }

    // ---- Phase C: PV over 64 tokens. Lane owns dims {2*lane, 2*lane+1}. ----
    float acc[GS][2];
    #pragma unroll
    for (int g = 0; g < GS; ++g) { acc[g][0] = 0.f; acc[g][1] = 0.f; }
    #pragma unroll
    for (int t = 0; t < 32; t += 4) {
        float4 p4[GS];
        #pragma unroll
        for (int g = 0; g < GS; ++g) p4[g] = *(const float4*)&s_p[g][t];
        #pragma unroll
        for (int k = 0; k < 4; ++k) {
            const float2 vv = v1[t + k];
            #pragma unroll
            for (int g = 0; g < GS; ++g) {
                const float pk = (k == 0) ? p4[g].x : (k == 1) ? p4[g].y : (k == 2) ? p4[g].z : p4[g].w;
                acc[g][0] = fmaf(pk, vv.x, acc[g][0]);
                acc[g][1] = fmaf(pk, vv.y, acc[g][1]);
            }
        }
    }
    #pragma unroll
    for (int t = 0; t < 32; t += 4) {
        float4 p4[GS];
        #pragma unroll
        for (int g = 0; g < GS; ++g) p4[g] = *(const float4*)&s_p[g][32 + t];
        #pragma unroll
        for (int k = 0; k < 4; ++k) {
            const float2 vv = v2[t + k];
            #pragma unroll
            for (int g = 0; g < GS; ++g) {
                const float pk = (k == 0) ? p4[g].x : (k == 1) ? p4[g].y : (k == 2) ? p4[g].z : p4[g].w;
                acc[g][0] = fmaf(pk, vv.x, acc[g][0]);
                acc[g][1] = fmaf(pk, vv.y, acc[g][1]);
            }
        }
    }
    #pragma unroll
    for (int g = 0; g < GS; ++g) {
        *(float2*)(po + (pidx + g) * HD + lane * 2) = make_float2(acc[g][0], acc[g][1]);
    }
}

// ---------------- Kernel 3: combine chunk partials (two-phase, no serial rescale) ----------------
__global__ __launch_bounds__(128) void combine_kernel(
    const float* __restrict__ pm, const float* __restrict__ pl, const float* __restrict__ po,
    const int* __restrict__ cs, float* __restrict__ att)
{
    const int bx = blockIdx.x;
    const int r = bx / GS, g = bx % GS;
    const int nc = (cs[r] + 63) >> 6;    // 1..64
    const int tid = threadIdx.x;

    __shared__ float w_s[64];
    __shared__ float L_s;

    if (tid < 64) {
        const int c = tid;
        float m = -3.0e38f, l = 0.f;
        if (c < nc) {
            const size_t idx = (size_t)(r * NCHUNK + c) * GS + g;
            m = pm[idx]; l = pl[idx];
        }
        float M = m;
        #pragma unroll
        for (int s = 1; s < 64; s <<= 1) M = fmaxf(M, __shfl_xor(M, s));
        const float wgt = __expf(m - M);           // 0 for inactive lanes
        float L = l * wgt;
        #pragma unroll
        for (int s = 1; s < 64; s <<= 1) L += __shfl_xor(L, s);
        w_s[c] = wgt;
        if (c == 0) L_s = L;
    }
    __syncthreads();

    const int d = tid;                   // 0..127
    const size_t base = (size_t)r * NCHUNK * GS + g;
    float acc = 0.f;
    int c = 0;
    for (; c + 4 <= nc; c += 4) {
        const float a0 = po[(base + (size_t)(c + 0) * GS) * HD + d];
        const float a1 = po[(base + (size_t)(c + 1) * GS) * HD + d];
        const float a2 = po[(base + (size_t)(c + 2) * GS) * HD + d];
        const float a3 = po[(base + (size_t)(c + 3) * GS) * HD + d];
        acc += w_s[c] * a0 + w_s[c + 1] * a1 + w_s[c + 2] * a2 + w_s[c + 3] * a3;
    }
    for (; c < nc; ++c) {
        acc += w_s[c] * po[(base + (size_t)c * GS) * HD + d];
    }
    att[(size_t)(r * GS + g) * HD + d] = acc / L_s;
}

// ---------------- Kernel 4: O projection GEMV ----------------
__global__ __launch_bounds__(256) void oproj_kernel(
    const float* __restrict__ att, const float* __restrict__ ow, float* __restrict__ out)
{
    const int blk = blockIdx.x;
    const int tid = threadIdx.x;
    const int w = tid >> 6;
    const int f0 = blk * 4;

    const float4* wr0 = (const float4*)(ow + (size_t)(f0 + 0) * H);
    const float4* wr1 = (const float4*)(ow + (size_t)(f0 + 1) * H);
    const float4* wr2 = (const float4*)(ow + (size_t)(f0 + 2) * H);
    const float4* wr3 = (const float4*)(ow + (size_t)(f0 + 3) * H);
    const float4* a4 = (const float4*)att;

    float acc[4][8];
    #pragma unroll
    for (int i = 0; i < 4; ++i)
        #pragma unroll
        for (int b = 0; b < 8; ++b) acc[i][b] = 0.f;

    #pragma unroll
    for (int k = 0; k < 4; ++k) {
        const int c = tid + k * 256;
        if (c < 896) {
            float4 w0 = wr0[c], w1 = wr1[c], w2 = wr2[c], w3 = wr3[c];
            float4 hb[8];
            #pragma unroll
            for (int b = 0; b < 8; ++b) hb[b] = a4[b * 896 + c];
            #pragma unroll
            for (int b = 0; b < 8; ++b) {
                acc[0][b] += dot4(w0, hb[b]);
                acc[1][b] += dot4(w1, hb[b]);
                acc[2][b] += dot4(w2, hb[b]);
                acc[3][b] += dot4(w3, hb[b]);
            }
        }
    }
    #pragma unroll
    for (int i = 0; i < 4; ++i)
        #pragma unroll
        for (int b = 0; b < 8; ++b)
            #pragma unroll
            for (int m = 1; m < 64; m <<= 1)
                acc[i][b] += __shfl_xor(acc[i][b], m);

    __shared__ float part[4][32];
    if ((tid & 63) == 0) {
        #pragma unroll
        for (int i = 0; i < 4; ++i)
            #pragma unroll
            for (int b = 0; b < 8; ++b)
                part[w][i * 8 + b] = acc[i][b];
    }
    __syncthreads();
    if (tid < 32) {
        const int i = tid >> 3, b = tid & 7;
        out[b * H + f0 + i] = part[0][tid] + part[1][tid] + part[2][tid] + part[3][tid];
    }
}

extern "C" void kernel_launch(void* const* d_in, const int* in_sizes, int n_in,
                              void* d_out, int out_size, void* d_ws, size_t ws_size,
                              hipStream_t stream) {
    (void)in_sizes; (void)n_in; (void)out_size; (void)ws_size;
    const float* hid  = (const float*)d_in[0];
    const float* cosb = (const float*)d_in[1];
    const float* sinb = (const float*)d_in[2];
    const float* qw   = (const float*)d_in[3];
    const float* qb   = (const float*)d_in[4];
    const float* kw   = (const float*)d_in[5];
    const float* kb   = (const float*)d_in[6];
    const float* vw   = (const float*)d_in[7];
    const float* vb   = (const float*)d_in[8];
    const float* ow   = (const float*)d_in[9];
    const float* kpool = (const float*)d_in[10];   // READ-ONLY
    const float* vpool = (const float*)d_in[11];   // READ-ONLY
    const int* btab   = (const int*)d_in[12];
    const int* cs     = (const int*)d_in[13];

    float* ws   = (float*)d_ws;
    float* q    = ws;             // 28672
    float* kraw = q + 28672;      // 4096
    float* vraw = kraw + 4096;    // 4096
    float* att  = vraw + 4096;    // 28672
    float* pm   = att + 28672;    // R*NCHUNK*GS = 14336
    float* pl   = pm + 14336;     // 14336
    float* po   = pl + 14336;     // R*NCHUNK*GS*HD = 1835008 (~7.3 MB)

    hipLaunchKernelGGL(qkv_kernel, dim3(1152), dim3(256), 0, stream,
                       hid, qw, qb, kw, kb, vw, vb, q, kraw, vraw);
    hipLaunchKernelGGL(attn_partial_kernel, dim3(NCHUNK, R), dim3(64), 0, stream,
                       q, kpool, vpool, kraw, vraw, cosb, sinb, btab, cs, pm, pl, po);
    hipLaunchKernelGGL(combine_kernel, dim3(R * GS), dim3(128), 0, stream,
                       pm, pl, po, cs, att);
    hipLaunchKernelGGL(oproj_kernel, dim3(896), dim3(256), 0, stream,
                       att, ow, (float*)d_out);
}